// Round 1
// baseline (124.578 us; speedup 1.0000x reference)
//
#include <hip/hip_runtime.h>
#include <stdint.h>

#define T_STEPS 32
#define DECAY 0.951229424500714f   // exp(-1/20)

typedef __attribute__((ext_vector_type(4))) float f32x4;
typedef __attribute__((ext_vector_type(8))) short bf16x8;

typedef const void __attribute__((address_space(1)))* gptr_t;
typedef void __attribute__((address_space(3)))* sptr_t;

__device__ __forceinline__ unsigned short f2bf(float f) {
    unsigned u = __builtin_bit_cast(unsigned, f);
    return (unsigned short)((u + 0x7FFFu + ((u >> 16) & 1u)) >> 16);
}

// blocks [0, mBlocks): temporal leaky reduce x[M][T][D] -> mem[M][D] (bf16 bits)
// blocks [mBlocks, ...): convert W fp32 -> bf16
__global__ __launch_bounds__(256) void prep_kernel(
    const float* __restrict__ x, const float* __restrict__ W,
    unsigned short* __restrict__ mem, unsigned short* __restrict__ Wb,
    int mBlocks, int M, int D)
{
    if ((int)blockIdx.x < mBlocks) {
        int idx = blockIdx.x * 256 + threadIdx.x;   // one per 4 floats of mem
        int perRow = D >> 2;                         // float4 per row
        int m = idx / perRow;
        int d4 = idx - m * perRow;
        if (m >= M) return;
        const f32x4* xr = (const f32x4*)(x + (size_t)m * T_STEPS * D) + d4;
        f32x4 acc = {0.f, 0.f, 0.f, 0.f};
        #pragma unroll
        for (int t = 0; t < T_STEPS; ++t) {
            f32x4 v = xr[(size_t)t * perRow];
            acc = acc * DECAY + v;                   // mem = sum_t decay^(T-1-t) x_t
        }
        ushort4 o;
        o.x = f2bf(acc.x); o.y = f2bf(acc.y); o.z = f2bf(acc.z); o.w = f2bf(acc.w);
        *(ushort4*)(mem + (size_t)idx * 4) = o;
    } else {
        int idx = (blockIdx.x - mBlocks) * 256 + threadIdx.x;
        f32x4 v = ((const f32x4*)W)[idx];
        ushort4 o;
        o.x = f2bf(v.x); o.y = f2bf(v.y); o.z = f2bf(v.z); o.w = f2bf(v.w);
        *(ushort4*)(Wb + (size_t)idx * 4) = o;
    }
}

// C[M][N] = A[M][K] @ B[N][K]^T + bias, bf16 inputs, fp32 out
#define BM 64
#define BN 64
#define BK 32

__global__ __launch_bounds__(256) void gemm_kernel(
    const unsigned short* __restrict__ A,    // mem bf16 [M][K]
    const unsigned short* __restrict__ Bw,   // W bf16 [N][K]
    const float* __restrict__ bias,          // [N]
    float* __restrict__ C,                   // [M][N]
    int M, int N, int K)
{
    __shared__ unsigned short As[BM][BK];   // 4 KiB
    __shared__ unsigned short Bs[BN][BK];   // 4 KiB

    int nbn = N / BN;
    int bm = blockIdx.x / nbn;
    int bn = blockIdx.x % nbn;

    int tid  = threadIdx.x;
    int lane = tid & 63;
    int wid  = tid >> 6;         // 0..3
    int wr   = wid >> 1;         // 2x2 wave grid; wave tile 32x32
    int wc   = wid & 1;

    // staging: 256 threads x 16B == whole 64x32 bf16 tile, LDS dest byte = 16*tid (linear)
    int srow = tid >> 2;         // 0..63
    int scol = (tid & 3) << 3;   // 0,8,16,24 (bf16 elems)

    const unsigned short* Ag = A  + (size_t)(bm * BM + srow) * K + scol;
    const unsigned short* Bg = Bw + (size_t)(bn * BN + srow) * K + scol;

    f32x4 acc[2][2] = {{{0.f,0.f,0.f,0.f},{0.f,0.f,0.f,0.f}},
                       {{0.f,0.f,0.f,0.f},{0.f,0.f,0.f,0.f}}};

    int fr = lane & 15;          // row within 16x16 fragment
    int fk = (lane >> 4) << 3;   // k offset (8 bf16 per lane)

    for (int k0 = 0; k0 < K; k0 += BK) {
        __builtin_amdgcn_global_load_lds((gptr_t)(Ag + k0), (sptr_t)(&As[srow][scol]), 16, 0, 0);
        __builtin_amdgcn_global_load_lds((gptr_t)(Bg + k0), (sptr_t)(&Bs[srow][scol]), 16, 0, 0);
        __syncthreads();   // compiler emits s_waitcnt vmcnt(0) before s_barrier

        bf16x8 a0 = *(const bf16x8*)&As[wr * 32 +      fr][fk];
        bf16x8 a1 = *(const bf16x8*)&As[wr * 32 + 16 + fr][fk];
        bf16x8 b0 = *(const bf16x8*)&Bs[wc * 32 +      fr][fk];
        bf16x8 b1 = *(const bf16x8*)&Bs[wc * 32 + 16 + fr][fk];

        acc[0][0] = __builtin_amdgcn_mfma_f32_16x16x32_bf16(a0, b0, acc[0][0], 0, 0, 0);
        acc[0][1] = __builtin_amdgcn_mfma_f32_16x16x32_bf16(a0, b1, acc[0][1], 0, 0, 0);
        acc[1][0] = __builtin_amdgcn_mfma_f32_16x16x32_bf16(a1, b0, acc[1][0], 0, 0, 0);
        acc[1][1] = __builtin_amdgcn_mfma_f32_16x16x32_bf16(a1, b1, acc[1][1], 0, 0, 0);

        __syncthreads();
    }

    // C/D layout: col = lane&15, row = (lane>>4)*4 + reg
    int fc  = lane & 15;
    int fq  = (lane >> 4) << 2;
    int row0 = bm * BM + wr * 32;
    int col0 = bn * BN + wc * 32;
    #pragma unroll
    for (int mi = 0; mi < 2; ++mi) {
        #pragma unroll
        for (int ni = 0; ni < 2; ++ni) {
            int col = col0 + ni * 16 + fc;
            float bv = bias[col];
            #pragma unroll
            for (int r = 0; r < 4; ++r) {
                int row = row0 + mi * 16 + fq + r;
                C[(size_t)row * N + col] = acc[mi][ni][r] + bv;
            }
        }
    }
}

extern "C" void kernel_launch(void* const* d_in, const int* in_sizes, int n_in,
                              void* d_out, int out_size, void* d_ws, size_t ws_size,
                              hipStream_t stream) {
    const float* x    = (const float*)d_in[0];
    const float* W    = (const float*)d_in[1];
    const float* bias = (const float*)d_in[2];
    float* out = (float*)d_out;

    int Dout = in_sizes[2];                   // 1024
    int Din  = in_sizes[1] / Dout;            // 1024
    int M    = in_sizes[0] / (T_STEPS * Din); // 4096 (= B*S)

    unsigned short* mem = (unsigned short*)d_ws;                      // M*Din bf16
    unsigned short* Wb  = (unsigned short*)d_ws + (size_t)M * Din;    // Dout*Din bf16

    int mBlocks = (M * Din) / (4 * 256);      // 4096
    int wBlocks = (Dout * Din) / (4 * 256);   // 1024
    prep_kernel<<<mBlocks + wBlocks, 256, 0, stream>>>(x, W, mem, Wb, mBlocks, M, Din);

    int grid = (M / BM) * (Dout / BN);        // 1024
    gemm_kernel<<<grid, 256, 0, stream>>>(mem, Wb, bias, out, M, Dout, Din);
}

// Round 2
// 123.514 us; speedup vs baseline: 1.0086x; 1.0086x over previous
//
#include <hip/hip_runtime.h>
#include <stdint.h>

#define T_STEPS 32
#define DECAY   0.951229424500714f    // exp(-1/20)
#define DECAY16 0.449328964117222f    // exp(-16/20)

typedef __attribute__((ext_vector_type(4))) float f32x4;
typedef __attribute__((ext_vector_type(8))) short bf16x8;

typedef const void __attribute__((address_space(1)))* gptr_t;
typedef void __attribute__((address_space(3)))* sptr_t;

__device__ __forceinline__ unsigned short f2bf(float f) {
    unsigned u = __builtin_bit_cast(unsigned, f);
    return (unsigned short)((u + 0x7FFFu + ((u >> 16) & 1u)) >> 16);
}

// blocks [0, mBlocks): temporal leaky reduce x[M][T][D] -> mem[M][D] (bf16 bits)
// blocks [mBlocks, ...): convert W fp32 -> bf16
__global__ __launch_bounds__(256) void prep_kernel(
    const float* __restrict__ x, const float* __restrict__ W,
    unsigned short* __restrict__ mem, unsigned short* __restrict__ Wb,
    int mBlocks, int M, int D)
{
    if ((int)blockIdx.x < mBlocks) {
        int idx = blockIdx.x * 256 + threadIdx.x;   // one per 4 floats of mem
        int perRow = D >> 2;                        // float4 per row
        int m = idx / perRow;
        int d4 = idx - m * perRow;
        if (m >= M) return;
        const f32x4* xr = (const f32x4*)(x + (size_t)m * T_STEPS * D) + d4;
        // two independent 16-long chains for load ILP; result = hi*d^16 + lo
        f32x4 accH = {0.f, 0.f, 0.f, 0.f};
        f32x4 accL = {0.f, 0.f, 0.f, 0.f};
        #pragma unroll
        for (int t = 0; t < 16; ++t) {
            f32x4 vh = xr[(size_t)t * perRow];
            f32x4 vl = xr[(size_t)(t + 16) * perRow];
            accH = accH * DECAY + vh;
            accL = accL * DECAY + vl;
        }
        f32x4 acc = accH * DECAY16 + accL;
        ushort4 o;
        o.x = f2bf(acc.x); o.y = f2bf(acc.y); o.z = f2bf(acc.z); o.w = f2bf(acc.w);
        *(ushort4*)(mem + (size_t)idx * 4) = o;
    } else {
        int idx = (blockIdx.x - mBlocks) * 256 + threadIdx.x;
        f32x4 v = ((const f32x4*)W)[idx];
        ushort4 o;
        o.x = f2bf(v.x); o.y = f2bf(v.y); o.z = f2bf(v.z); o.w = f2bf(v.w);
        *(ushort4*)(Wb + (size_t)idx * 4) = o;
    }
}

// C[M][N] = A[M][K] @ B[N][K]^T + bias, bf16 inputs, fp32 out
// 64x128 tile, BK=32, 4 waves (2x2), wave tile 32x64, double-buffered LDS.
#define BM 64
#define BN 128
#define BK 32

__global__ __launch_bounds__(256) void gemm_kernel(
    const unsigned short* __restrict__ A,    // mem bf16 [M][K]
    const unsigned short* __restrict__ Bw,   // W bf16 [N][K]
    const float* __restrict__ bias,          // [N]
    float* __restrict__ C,                   // [M][N]
    int M, int N, int K)
{
    __shared__ unsigned short As[2][BM][BK];   // 2 x 4 KiB
    __shared__ unsigned short Bs[2][BN][BK];   // 2 x 8 KiB

    int nbn = N / BN;
    int bm = blockIdx.x / nbn;
    int bn = blockIdx.x % nbn;

    int tid  = threadIdx.x;
    int lane = tid & 63;
    int wid  = tid >> 6;         // 0..3
    int wr   = wid >> 1;         // wave row block (32 rows)
    int wc   = wid & 1;          // wave col block (64 cols)

    // staging: LDS dest byte = 16*tid within each 4 KiB chunk (linear, rule 21)
    int srow = tid >> 2;         // 0..63
    int scol = (tid & 3) << 3;   // bf16 elems 0,8,16,24

    const unsigned short* Ag  = A  + (size_t)(bm * BM + srow) * K + scol;
    const unsigned short* Bg0 = Bw + (size_t)(bn * BN + srow) * K + scol;
    const unsigned short* Bg1 = Bw + (size_t)(bn * BN + 64 + srow) * K + scol;

    f32x4 acc[2][4] = {};

    int fr = lane & 15;          // row within 16x16 fragment
    int fk = (lane >> 4) << 3;   // k offset (8 bf16 per lane)

    auto stage = [&](int b, int k0) {
        __builtin_amdgcn_global_load_lds((gptr_t)(Ag  + k0), (sptr_t)(&As[b][srow][scol]),      16, 0, 0);
        __builtin_amdgcn_global_load_lds((gptr_t)(Bg0 + k0), (sptr_t)(&Bs[b][srow][scol]),      16, 0, 0);
        __builtin_amdgcn_global_load_lds((gptr_t)(Bg1 + k0), (sptr_t)(&Bs[b][64 + srow][scol]), 16, 0, 0);
    };

    stage(0, 0);
    __syncthreads();

    int nk = K / BK;
    for (int kt = 0; kt < nk; ++kt) {
        int cur = kt & 1;
        if (kt + 1 < nk) stage(cur ^ 1, (kt + 1) * BK);   // prefetch next tile

        // conflict-free: each read = 16 rows x 4 slots = contiguous 1 KiB
        bf16x8 a0 = *(const bf16x8*)&As[cur][wr * 32 +      fr][fk];
        bf16x8 a1 = *(const bf16x8*)&As[cur][wr * 32 + 16 + fr][fk];
        bf16x8 b0 = *(const bf16x8*)&Bs[cur][wc * 64 +      fr][fk];
        bf16x8 b1 = *(const bf16x8*)&Bs[cur][wc * 64 + 16 + fr][fk];
        bf16x8 b2 = *(const bf16x8*)&Bs[cur][wc * 64 + 32 + fr][fk];
        bf16x8 b3 = *(const bf16x8*)&Bs[cur][wc * 64 + 48 + fr][fk];

        acc[0][0] = __builtin_amdgcn_mfma_f32_16x16x32_bf16(a0, b0, acc[0][0], 0, 0, 0);
        acc[0][1] = __builtin_amdgcn_mfma_f32_16x16x32_bf16(a0, b1, acc[0][1], 0, 0, 0);
        acc[0][2] = __builtin_amdgcn_mfma_f32_16x16x32_bf16(a0, b2, acc[0][2], 0, 0, 0);
        acc[0][3] = __builtin_amdgcn_mfma_f32_16x16x32_bf16(a0, b3, acc[0][3], 0, 0, 0);
        acc[1][0] = __builtin_amdgcn_mfma_f32_16x16x32_bf16(a1, b0, acc[1][0], 0, 0, 0);
        acc[1][1] = __builtin_amdgcn_mfma_f32_16x16x32_bf16(a1, b1, acc[1][1], 0, 0, 0);
        acc[1][2] = __builtin_amdgcn_mfma_f32_16x16x32_bf16(a1, b2, acc[1][2], 0, 0, 0);
        acc[1][3] = __builtin_amdgcn_mfma_f32_16x16x32_bf16(a1, b3, acc[1][3], 0, 0, 0);

        __syncthreads();   // drains vmcnt (next stage done) + lgkmcnt (reads done)
    }

    // C/D layout: col = lane&15, row = (lane>>4)*4 + reg
    int fc  = lane & 15;
    int fq  = (lane >> 4) << 2;
    int row0 = bm * BM + wr * 32;
    int col0 = bn * BN + wc * 64;
    #pragma unroll
    for (int mi = 0; mi < 2; ++mi) {
        #pragma unroll
        for (int ni = 0; ni < 4; ++ni) {
            int col = col0 + ni * 16 + fc;
            float bv = bias[col];
            #pragma unroll
            for (int r = 0; r < 4; ++r) {
                int row = row0 + mi * 16 + fq + r;
                C[(size_t)row * N + col] = acc[mi][ni][r] + bv;
            }
        }
    }
}

extern "C" void kernel_launch(void* const* d_in, const int* in_sizes, int n_in,
                              void* d_out, int out_size, void* d_ws, size_t ws_size,
                              hipStream_t stream) {
    const float* x    = (const float*)d_in[0];
    const float* W    = (const float*)d_in[1];
    const float* bias = (const float*)d_in[2];
    float* out = (float*)d_out;

    int Dout = in_sizes[2];                   // 1024
    int Din  = in_sizes[1] / Dout;            // 1024
    int M    = in_sizes[0] / (T_STEPS * Din); // 4096 (= B*S)

    unsigned short* mem = (unsigned short*)d_ws;                      // M*Din bf16
    unsigned short* Wb  = (unsigned short*)d_ws + (size_t)M * Din;    // Dout*Din bf16

    int mBlocks = (M * Din) / (4 * 256);      // 4096
    int wBlocks = (Dout * Din) / (4 * 256);   // 1024
    prep_kernel<<<mBlocks + wBlocks, 256, 0, stream>>>(x, W, mem, Wb, mBlocks, M, Din);

    int grid = (M / BM) * (Dout / BN);        // 512
    gemm_kernel<<<grid, 256, 0, stream>>>(mem, Wb, bias, out, M, Dout, Din);
}

// Round 3
// 113.742 us; speedup vs baseline: 1.0953x; 1.0859x over previous
//
#include <hip/hip_runtime.h>
#include <stdint.h>

#define T_STEPS 32
#define DECAY   0.951229424500714f    // exp(-1/20)
#define DECAY16 0.449328964117222f    // exp(-16/20)

typedef __attribute__((ext_vector_type(4))) float f32x4;
typedef __attribute__((ext_vector_type(8))) short bf16x8;

typedef const void __attribute__((address_space(1)))* gptr_t;
typedef void __attribute__((address_space(3)))* sptr_t;

__device__ __forceinline__ unsigned short f2bf(float f) {
    unsigned u = __builtin_bit_cast(unsigned, f);
    return (unsigned short)((u + 0x7FFFu + ((u >> 16) & 1u)) >> 16);
}

// blocks [0, mBlocks): temporal leaky reduce x[M][T][D] -> mem[M][D] (bf16 bits)
// blocks [mBlocks, ...): convert W fp32 -> bf16
__global__ __launch_bounds__(256) void prep_kernel(
    const float* __restrict__ x, const float* __restrict__ W,
    unsigned short* __restrict__ mem, unsigned short* __restrict__ Wb,
    int mBlocks, int M, int D)
{
    if ((int)blockIdx.x < mBlocks) {
        int idx = blockIdx.x * 256 + threadIdx.x;   // one per 4 floats of mem
        int perRow = D >> 2;                        // float4 per row
        int m = idx / perRow;
        int d4 = idx - m * perRow;
        if (m >= M) return;
        const f32x4* xr = (const f32x4*)(x + (size_t)m * T_STEPS * D) + d4;
        // two independent 16-long chains for load ILP; result = hi*d^16 + lo
        f32x4 accH = {0.f, 0.f, 0.f, 0.f};
        f32x4 accL = {0.f, 0.f, 0.f, 0.f};
        #pragma unroll
        for (int t = 0; t < 16; ++t) {
            f32x4 vh = __builtin_nontemporal_load(&xr[(size_t)t * perRow]);
            f32x4 vl = __builtin_nontemporal_load(&xr[(size_t)(t + 16) * perRow]);
            accH = accH * DECAY + vh;
            accL = accL * DECAY + vl;
        }
        f32x4 acc = accH * DECAY16 + accL;
        ushort4 o;
        o.x = f2bf(acc.x); o.y = f2bf(acc.y); o.z = f2bf(acc.z); o.w = f2bf(acc.w);
        *(ushort4*)(mem + (size_t)idx * 4) = o;
    } else {
        int idx = (blockIdx.x - mBlocks) * 256 + threadIdx.x;
        f32x4 v = ((const f32x4*)W)[idx];
        ushort4 o;
        o.x = f2bf(v.x); o.y = f2bf(v.y); o.z = f2bf(v.z); o.w = f2bf(v.w);
        *(ushort4*)(Wb + (size_t)idx * 4) = o;
    }
}

// C[M][N] = A[M][K] @ B[N][K]^T + bias, bf16 inputs, fp32 out
// 64x128 tile, BK=32, 4 waves (2x2), wave tile 32x64.
// Triple-buffered LDS, counted vmcnt (never 0 in loop), raw s_barrier.
#define BM 64
#define BN 128
#define BK 32

__global__ __launch_bounds__(256) void gemm_kernel(
    const unsigned short* __restrict__ A,    // mem bf16 [M][K]
    const unsigned short* __restrict__ Bw,   // W bf16 [N][K]
    const float* __restrict__ bias,          // [N]
    float* __restrict__ C,                   // [M][N]
    int M, int N, int K)
{
    __shared__ unsigned short As[3][BM][BK];   // 3 x 4 KiB
    __shared__ unsigned short Bs[3][BN][BK];   // 3 x 8 KiB

    // XCD-aware swizzle: 64 consecutive wgs per XCD (grid=512, 512%8==0 bijective)
    int nwg = gridDim.x;
    int cpx = nwg >> 3;
    int bid = (int)blockIdx.x;
    int wg  = (bid & 7) * cpx + (bid >> 3);

    int nbn = N / BN;
    int bm = wg / nbn;
    int bn = wg % nbn;

    int tid  = threadIdx.x;
    int lane = tid & 63;
    int wid  = tid >> 6;         // 0..3
    int wr   = wid >> 1;         // wave row block (32 rows)
    int wc   = wid & 1;          // wave col block (64 cols)

    // staging: LDS dest byte = 16*tid within each chunk (linear, rule 21)
    int srow = tid >> 2;         // 0..63
    int scol = (tid & 3) << 3;   // bf16 elems 0,8,16,24

    const unsigned short* Ag  = A  + (size_t)(bm * BM + srow) * K + scol;
    const unsigned short* Bg0 = Bw + (size_t)(bn * BN + srow) * K + scol;
    const unsigned short* Bg1 = Bw + (size_t)(bn * BN + 64 + srow) * K + scol;

    f32x4 acc[2][4] = {};

    int fr = lane & 15;          // row within 16x16 fragment
    int fk = (lane >> 4) << 3;   // k offset (8 bf16 per lane)

    auto stage = [&](int b, int kt) {
        int k0 = kt * BK;
        __builtin_amdgcn_global_load_lds((gptr_t)(Ag  + k0), (sptr_t)(&As[b][srow][scol]),      16, 0, 0);
        __builtin_amdgcn_global_load_lds((gptr_t)(Bg0 + k0), (sptr_t)(&Bs[b][srow][scol]),      16, 0, 0);
        __builtin_amdgcn_global_load_lds((gptr_t)(Bg1 + k0), (sptr_t)(&Bs[b][64 + srow][scol]), 16, 0, 0);
    };

    int nk = K / BK;             // 32

    stage(0, 0);
    stage(1, 1);                 // 6 loads outstanding
    asm volatile("s_waitcnt vmcnt(3)" ::: "memory");   // buf0 landed
    __builtin_amdgcn_s_barrier();

    for (int kt = 0; kt < nk; ++kt) {
        int cur = kt % 3;
        if (kt + 2 < nk) stage((kt + 2) % 3, kt + 2);   // keep pipeline 2 deep

        bf16x8 a0 = *(const bf16x8*)&As[cur][wr * 32 +      fr][fk];
        bf16x8 a1 = *(const bf16x8*)&As[cur][wr * 32 + 16 + fr][fk];
        bf16x8 b0 = *(const bf16x8*)&Bs[cur][wc * 64 +      fr][fk];
        bf16x8 b1 = *(const bf16x8*)&Bs[cur][wc * 64 + 16 + fr][fk];
        bf16x8 b2 = *(const bf16x8*)&Bs[cur][wc * 64 + 32 + fr][fk];
        bf16x8 b3 = *(const bf16x8*)&Bs[cur][wc * 64 + 48 + fr][fk];

        acc[0][0] = __builtin_amdgcn_mfma_f32_16x16x32_bf16(a0, b0, acc[0][0], 0, 0, 0);
        acc[0][1] = __builtin_amdgcn_mfma_f32_16x16x32_bf16(a0, b1, acc[0][1], 0, 0, 0);
        acc[0][2] = __builtin_amdgcn_mfma_f32_16x16x32_bf16(a0, b2, acc[0][2], 0, 0, 0);
        acc[0][3] = __builtin_amdgcn_mfma_f32_16x16x32_bf16(a0, b3, acc[0][3], 0, 0, 0);
        acc[1][0] = __builtin_amdgcn_mfma_f32_16x16x32_bf16(a1, b0, acc[1][0], 0, 0, 0);
        acc[1][1] = __builtin_amdgcn_mfma_f32_16x16x32_bf16(a1, b1, acc[1][1], 0, 0, 0);
        acc[1][2] = __builtin_amdgcn_mfma_f32_16x16x32_bf16(a1, b2, acc[1][2], 0, 0, 0);
        acc[1][3] = __builtin_amdgcn_mfma_f32_16x16x32_bf16(a1, b3, acc[1][3], 0, 0, 0);

        // ensure next buffer's stage has landed before crossing the barrier;
        // never drain to 0 while loads are still wanted in flight
        if (kt + 2 < nk) {
            asm volatile("s_waitcnt vmcnt(3)" ::: "memory");   // stage(kt+1) done
            __builtin_amdgcn_s_barrier();
        } else if (kt + 1 < nk) {
            asm volatile("s_waitcnt vmcnt(0)" ::: "memory");   // last stage done
            __builtin_amdgcn_s_barrier();
        }
    }

    // C/D layout: col = lane&15, row = (lane>>4)*4 + reg
    int fc  = lane & 15;
    int fq  = (lane >> 4) << 2;
    int row0 = bm * BM + wr * 32;
    int col0 = bn * BN + wc * 64;
    #pragma unroll
    for (int mi = 0; mi < 2; ++mi) {
        #pragma unroll
        for (int ni = 0; ni < 4; ++ni) {
            int col = col0 + ni * 16 + fc;
            float bv = bias[col];
            #pragma unroll
            for (int r = 0; r < 4; ++r) {
                int row = row0 + mi * 16 + fq + r;
                C[(size_t)row * N + col] = acc[mi][ni][r] + bv;
            }
        }
    }
}

extern "C" void kernel_launch(void* const* d_in, const int* in_sizes, int n_in,
                              void* d_out, int out_size, void* d_ws, size_t ws_size,
                              hipStream_t stream) {
    const float* x    = (const float*)d_in[0];
    const float* W    = (const float*)d_in[1];
    const float* bias = (const float*)d_in[2];
    float* out = (float*)d_out;

    int Dout = in_sizes[2];                   // 1024
    int Din  = in_sizes[1] / Dout;            // 1024
    int M    = in_sizes[0] / (T_STEPS * Din); // 4096 (= B*S)

    unsigned short* mem = (unsigned short*)d_ws;                      // M*Din bf16
    unsigned short* Wb  = (unsigned short*)d_ws + (size_t)M * Din;    // Dout*Din bf16

    int mBlocks = (M * Din) / (4 * 256);      // 4096
    int wBlocks = (Dout * Din) / (4 * 256);   // 1024
    prep_kernel<<<mBlocks + wBlocks, 256, 0, stream>>>(x, W, mem, Wb, mBlocks, M, Din);

    int grid = (M / BM) * (Dout / BN);        // 512
    gemm_kernel<<<grid, 256, 0, stream>>>(mem, Wb, bias, out, M, Dout, Din);
}